// Round 3
// baseline (490.653 us; speedup 1.0000x reference)
//
#include <hip/hip_runtime.h>
#include <stdint.h>

#define SEQS 64
#define QL 4
#define KL 2048
#define NH 32
#define KVH 4
#define GRP 8
#define DN 128
#define DR 64
#define BS 16
#define SPLIT 2
#define CPW 8              // chunks (32 tok) per wave = KL/SPLIT/4waves/32
#define WS_STRIDE 4160     // floats per partial slot: 32 qcols x 128 dims + m[32] + l[32]

typedef __attribute__((ext_vector_type(4))) float f32x4;
typedef __attribute__((ext_vector_type(8))) short s16x8;

#define VT_STRIDE 40   // shorts per V^T dim-row: 32 tokens + 8 pad
#define P_STRIDE  40   // shorts per P qrow

__device__ __forceinline__ short f2bf(float f) {
    union { float f; uint32_t u; } v; v.f = f;
    uint32_t r = (v.u + 0x7FFFu + ((v.u >> 16) & 1u)) >> 16;  // RNE
    return (short)r;
}

__device__ __forceinline__ s16x8 cvt8(f32x4 a, f32x4 b) {
    s16x8 r;
    r[0] = f2bf(a[0]); r[1] = f2bf(a[1]); r[2] = f2bf(a[2]); r[3] = f2bf(a[3]);
    r[4] = f2bf(b[0]); r[5] = f2bf(b[1]); r[6] = f2bf(b[2]); r[7] = f2bf(b[3]);
    return r;
}

// grid: 512 blocks = (seq, kv_head, K-split); 256 threads = 4 waves; wave owns 256 tokens.
// 2 blocks/CU -> 2 waves/SIMD: TLP hides gather latency that 1 wave/SIMD could not.
__global__ __launch_bounds__(256, 2) void mla_partial(
    const float* __restrict__ qn, const float* __restrict__ qr,
    const float* __restrict__ kn, const float* __restrict__ kr,
    const int* __restrict__ bt, float* __restrict__ ws)
{
    __shared__ __align__(16) char smem[51200];

    const int tid = threadIdx.x;
    const int w   = tid >> 6;
    const int l   = tid & 63;
    const int bid = blockIdx.x;
    const int split = bid & 1;
    const int sh  = bid >> 1;
    const int s   = sh >> 2;
    const int h   = sh & 3;
    const int l15 = l & 15;
    const int l4  = l >> 4;

    short* Vt = (short*)smem + w * (DN * VT_STRIDE);
    short* Pl = (short*)(smem + 4 * DN * VT_STRIDE * 2) + w * (32 * P_STRIDE);

    // ---- Q fragments (B-layout, resident): qf[ks][nt]
    s16x8 qf[6][2];
    #pragma unroll
    for (int nt = 0; nt < 2; ++nt) {
        int qcol = l15 + 16 * nt;
        int qpos = qcol >> 3, g = qcol & 7;
        const float* qnb = qn + ((size_t)((s*QL + qpos)*NH + h*GRP + g)) * DN + l4*8;
        const float* qrb = qr + ((size_t)((s*QL + qpos)*NH + h*GRP + g)) * DR + l4*8;
        #pragma unroll
        for (int ks = 0; ks < 4; ++ks) {
            f32x4 a = *(const f32x4*)(qnb + 32*ks);
            f32x4 b = *(const f32x4*)(qnb + 32*ks + 4);
            qf[ks][nt] = cvt8(a, b);
        }
        #pragma unroll
        for (int ks = 0; ks < 2; ++ks) {
            f32x4 a = *(const f32x4*)(qrb + 32*ks);
            f32x4 b = *(const f32x4*)(qrb + 32*ks + 4);
            qf[4+ks][nt] = cvt8(a, b);
        }
    }

    const float scale = 0.07216878364870322f;  // 1/sqrt(192)

    f32x4 of[8][2];
    #pragma unroll
    for (int mt = 0; mt < 8; ++mt)
        #pragma unroll
        for (int nt = 0; nt < 2; ++nt) of[mt][nt] = f32x4{0.f, 0.f, 0.f, 0.f};
    float m2[2] = {-INFINITY, -INFINITY};
    float l2[2] = {0.f, 0.f};

    const int btbase = s * (KL / BS) + split * (KL / BS / SPLIT) + w * (CPW * 2);
    const int btreg = bt[btbase + l15];   // 16 kv-block ids, lane-indexed

    auto loadK = [&](int blkv, f32x4* dst) {
        int blk = __builtin_amdgcn_readfirstlane(blkv);
        const float* knb = kn + ((size_t)(blk*BS + l15)*KVH + h) * DN + l4*8;
        const float* krb = kr + ((size_t)(blk*BS + l15)*KVH + h) * DR + l4*8;
        #pragma unroll
        for (int ks = 0; ks < 4; ++ks) {
            dst[2*ks]   = *(const f32x4*)(knb + 32*ks);
            dst[2*ks+1] = *(const f32x4*)(knb + 32*ks + 4);
        }
        #pragma unroll
        for (int ks = 0; ks < 2; ++ks) {
            dst[8+2*ks]   = *(const f32x4*)(krb + 32*ks);
            dst[8+2*ks+1] = *(const f32x4*)(krb + 32*ks + 4);
        }
    };

    f32x4 buf0[12], buf1[12];
    loadK(__shfl(btreg, 0, 64), buf0);

    #pragma unroll 1
    for (int c = 0; c < CPW; ++c) {
        f32x4 sf[2][2];
        #pragma unroll
        for (int mt = 0; mt < 2; ++mt)
            #pragma unroll
            for (int nt = 0; nt < 2; ++nt) sf[mt][nt] = f32x4{0.f, 0.f, 0.f, 0.f};

        auto qkstep = [&](const f32x4* ld, int mt) {
            s16x8 af[6];
            #pragma unroll
            for (int ks = 0; ks < 6; ++ks) af[ks] = cvt8(ld[2*ks], ld[2*ks+1]);
            #pragma unroll
            for (int ks = 0; ks < 4; ++ks) {
                int dbase = l4*8 + 32*ks;
                #pragma unroll
                for (int j = 0; j < 8; ++j)
                    Vt[(dbase + j) * VT_STRIDE + 16*mt + l15] = af[ks][j];
            }
            #pragma unroll
            for (int ks = 0; ks < 6; ++ks) {
                sf[mt][0] = __builtin_amdgcn_mfma_f32_16x16x32_bf16(af[ks], qf[ks][0], sf[mt][0], 0, 0, 0);
                sf[mt][1] = __builtin_amdgcn_mfma_f32_16x16x32_bf16(af[ks], qf[ks][1], sf[mt][1], 0, 0, 0);
            }
        };

        loadK(__shfl(btreg, 2*c + 1, 64), buf1);
        qkstep(buf0, 0);
        if (c + 1 < CPW)
            loadK(__shfl(btreg, 2*c + 2, 64), buf0);
        qkstep(buf1, 1);

        // ---- online softmax over 32 tokens
        float cmax[2] = {-INFINITY, -INFINITY};
        #pragma unroll
        for (int mt = 0; mt < 2; ++mt)
            #pragma unroll
            for (int nt = 0; nt < 2; ++nt)
                #pragma unroll
                for (int r = 0; r < 4; ++r) cmax[nt] = fmaxf(cmax[nt], sf[mt][nt][r]);
        #pragma unroll
        for (int nt = 0; nt < 2; ++nt) {
            cmax[nt] = fmaxf(cmax[nt], __shfl_xor(cmax[nt], 16, 64));
            cmax[nt] = fmaxf(cmax[nt], __shfl_xor(cmax[nt], 32, 64));
        }
        float alpha[2], psum[2];
        #pragma unroll
        for (int nt = 0; nt < 2; ++nt) {
            float mn = fmaxf(m2[nt], cmax[nt] * scale);
            alpha[nt] = __expf(m2[nt] - mn);
            m2[nt] = mn;
            psum[nt] = 0.f;
        }
        float p[2][2][4];
        #pragma unroll
        for (int mt = 0; mt < 2; ++mt)
            #pragma unroll
            for (int nt = 0; nt < 2; ++nt)
                #pragma unroll
                for (int r = 0; r < 4; ++r) {
                    float e = __expf(sf[mt][nt][r] * scale - m2[nt]);
                    p[mt][nt][r] = e; psum[nt] += e;
                }
        #pragma unroll
        for (int nt = 0; nt < 2; ++nt) {
            psum[nt] += __shfl_xor(psum[nt], 16, 64);
            psum[nt] += __shfl_xor(psum[nt], 32, 64);
            l2[nt] = l2[nt] * alpha[nt] + psum[nt];
        }
        #pragma unroll
        for (int mt = 0; mt < 8; ++mt)
            #pragma unroll
            for (int nt = 0; nt < 2; ++nt) {
                of[mt][nt][0] *= alpha[nt]; of[mt][nt][1] *= alpha[nt];
                of[mt][nt][2] *= alpha[nt]; of[mt][nt][3] *= alpha[nt];
            }

        // ---- P round-trip through LDS
        #pragma unroll
        for (int mt = 0; mt < 2; ++mt)
            #pragma unroll
            for (int nt = 0; nt < 2; ++nt) {
                unsigned lo = (unsigned short)f2bf(p[mt][nt][0]) | ((unsigned)(unsigned short)f2bf(p[mt][nt][1]) << 16);
                unsigned hi = (unsigned short)f2bf(p[mt][nt][2]) | ((unsigned)(unsigned short)f2bf(p[mt][nt][3]) << 16);
                unsigned long long v = (unsigned long long)lo | ((unsigned long long)hi << 32);
                *(unsigned long long*)(Pl + (l15 + 16*nt) * P_STRIDE + 16*mt + l4*4) = v;
            }
        s16x8 pf[2];
        #pragma unroll
        for (int nt = 0; nt < 2; ++nt)
            pf[nt] = *(const s16x8*)(Pl + (l15 + 16*nt) * P_STRIDE + l4*8);

        // ---- O^T += V^T * P^T
        #pragma unroll
        for (int mt = 0; mt < 8; ++mt) {
            s16x8 vf = *(const s16x8*)(Vt + (l15 + 16*mt) * VT_STRIDE + l4*8);
            of[mt][0] = __builtin_amdgcn_mfma_f32_16x16x32_bf16(vf, pf[0], of[mt][0], 0, 0, 0);
            of[mt][1] = __builtin_amdgcn_mfma_f32_16x16x32_bf16(vf, pf[1], of[mt][1], 0, 0, 0);
        }
    }

    // ---- in-block cross-wave combine (tree, 2 fp32 LDS slots)
    auto dump = [&](int slot) {
        float* sp = (float*)smem + slot * 4160;
        #pragma unroll
        for (int mt = 0; mt < 8; ++mt)
            #pragma unroll
            for (int nt = 0; nt < 2; ++nt)
                #pragma unroll
                for (int r = 0; r < 4; ++r)
                    sp[(16*mt + l4*4 + r) * 32 + l15 + 16*nt] = of[mt][nt][r];
        if (l4 == 0) {
            sp[4096 + l15]      = m2[0]; sp[4096 + 16 + l15] = m2[1];
            sp[4128 + l15]      = l2[0]; sp[4128 + 16 + l15] = l2[1];
        }
    };
    auto merge = [&](int slot) {
        float* sp = (float*)smem + slot * 4160;
        float as[2], ao[2];
        #pragma unroll
        for (int nt = 0; nt < 2; ++nt) {
            int qcol = l15 + 16*nt;
            float mo = sp[4096 + qcol];
            float lo = sp[4128 + qcol];
            float mn = fmaxf(m2[nt], mo);
            as[nt] = __expf(m2[nt] - mn);
            ao[nt] = __expf(mo - mn);
            l2[nt] = l2[nt] * as[nt] + lo * ao[nt];
            m2[nt] = mn;
        }
        #pragma unroll
        for (int mt = 0; mt < 8; ++mt)
            #pragma unroll
            for (int nt = 0; nt < 2; ++nt)
                #pragma unroll
                for (int r = 0; r < 4; ++r)
                    of[mt][nt][r] = of[mt][nt][r] * as[nt]
                                  + sp[(16*mt + l4*4 + r) * 32 + l15 + 16*nt] * ao[nt];
    };

    __syncthreads();
    if (w & 1) dump(w >> 1);
    __syncthreads();
    if (!(w & 1)) merge(w >> 1);
    __syncthreads();
    if (w == 2) dump(0);
    __syncthreads();
    if (w == 0) {
        merge(0);
        // write raw partial (O^T, m, l), qcol-major, NO normalization
        float* wsb = ws + (size_t)bid * WS_STRIDE;
        #pragma unroll
        for (int nt = 0; nt < 2; ++nt) {
            int qcol = l15 + 16*nt;
            #pragma unroll
            for (int mt = 0; mt < 8; ++mt)
                *(f32x4*)(wsb + qcol*DN + 16*mt + l4*4) = of[mt][nt];
        }
        if (l4 == 0) {
            wsb[4096 + l15]      = m2[0]; wsb[4096 + 16 + l15] = m2[1];
            wsb[4128 + l15]      = l2[0]; wsb[4128 + 16 + l15] = l2[1];
        }
    }
}

// grid: 256 blocks = (seq, kv_head); 64 threads. Merge SPLIT partials, normalize, write out.
__global__ __launch_bounds__(64, 4) void mla_combine(
    const float* __restrict__ ws, float* __restrict__ out)
{
    const int sh = blockIdx.x;
    const int s = sh >> 2, h = sh & 3;
    const int l = threadIdx.x;
    const int qcol = l >> 1;
    const int hf = l & 1;

    const float* w0 = ws + (size_t)(sh * SPLIT + 0) * WS_STRIDE;
    const float* w1 = ws + (size_t)(sh * SPLIT + 1) * WS_STRIDE;

    float m0 = w0[4096 + qcol], m1 = w1[4096 + qcol];
    float s0 = w0[4128 + qcol], s1 = w1[4128 + qcol];
    float mn = fmaxf(m0, m1);
    float e0 = __expf(m0 - mn), e1 = __expf(m1 - mn);
    float inv = 1.f / (s0 * e0 + s1 * e1);
    e0 *= inv; e1 *= inv;

    const int qpos = qcol >> 3, g = qcol & 7;
    float* ob = out + ((size_t)((s*QL + qpos)*NH + h*GRP + g)) * DN + hf*64;
    const float* a0 = w0 + qcol*DN + hf*64;
    const float* a1 = w1 + qcol*DN + hf*64;
    #pragma unroll
    for (int i = 0; i < 16; ++i) {
        f32x4 x = *(const f32x4*)(a0 + 4*i);
        f32x4 y = *(const f32x4*)(a1 + 4*i);
        f32x4 v;
        v[0] = x[0]*e0 + y[0]*e1; v[1] = x[1]*e0 + y[1]*e1;
        v[2] = x[2]*e0 + y[2]*e1; v[3] = x[3]*e0 + y[3]*e1;
        *(f32x4*)(ob + 4*i) = v;
    }
}

extern "C" void kernel_launch(void* const* d_in, const int* in_sizes, int n_in,
                              void* d_out, int out_size, void* d_ws, size_t ws_size,
                              hipStream_t stream) {
    (void)in_sizes; (void)n_in; (void)out_size; (void)ws_size;
    const float* qn = (const float*)d_in[0];
    const float* qr = (const float*)d_in[1];
    const float* kn = (const float*)d_in[2];
    const float* kr = (const float*)d_in[3];
    const int*   bt = (const int*)d_in[4];
    float* ws  = (float*)d_ws;
    float* out = (float*)d_out;
    mla_partial<<<SEQS * KVH * SPLIT, 256, 0, stream>>>(qn, qr, kn, kr, bt, ws);
    mla_combine<<<SEQS * KVH, 64, 0, stream>>>(ws, out);
}